// Round 22
// baseline (178.060 us; speedup 1.0000x reference)
//
#include <hip/hip_runtime.h>
#include <hip/hip_bf16.h>
#include <stdint.h>

#define T_TOK 2048
#define HID   1024
#define FFN_  2048
#define NEXP  8
#define NPAIR 4096   // T_TOK * top_k(2)
#define MAXTILE 40   // sum over experts of ceil(cnt/128) <= 32+8
#define EXPELEM ((size_t)HID * FFN_)
#define NSLICE 16    // route slices (waves)
#define NGEMM (MAXTILE * (FFN_ / 64))   // 1280 = 8*160
#define NDOWN (MAXTILE * (HID / 64))    // 640  = 8*80

typedef __bf16 bf16;
typedef __bf16 bf16x8 __attribute__((ext_vector_type(8)));
typedef __bf16 bf16x4 __attribute__((ext_vector_type(4)));
typedef float  f32x4  __attribute__((ext_vector_type(4)));
typedef float  f32x4v __attribute__((ext_vector_type(4)));
typedef unsigned int u32;

// ---- workspace layout (bytes) ----
#define OFF_EXP   0
#define OFF_NT    64
#define OFF_TTE   128
#define OFF_TTM   512
#define OFF_TOK   1024
#define OFF_WGT   (OFF_TOK + 16384)
#define OFF_XG    65536
#define OFF_H1    (OFF_XG + (size_t)NPAIR*HID*2)
#define OFF_WT    (OFF_H1 + (size_t)NPAIR*FFN_*2)   // [wuT 32M][wgT 32M][wdT 32M]

__device__ __forceinline__ void gld16(const void* g, void* l) {
    __builtin_amdgcn_global_load_lds(
        (const __attribute__((address_space(1))) u32*)g,
        (__attribute__((address_space(3))) u32*)l, 16, 0, 0);
}

// XCD swizzle: all NB N-blocks of one ty share id%8 -> same XCD L2 keeps
// the shared A-panel resident. id = (ty%8) + 8*(bn + NB*(ty/8)); inverse:
__device__ __forceinline__ void xcd_decode(int bid, int NB, int& ty, int& bn) {
    int c = bid & 7, r = bid >> 3;
    bn = r % NB;
    ty = (r / NB) * 8 + c;
}

// ---------------- routing: two-level parallel counting sort -----------------
__global__ void __launch_bounds__(1024)
route_kernel(const uint32_t* __restrict__ te_raw,
             const float* __restrict__ top_w,
             int* __restrict__ expert_off,
             int* __restrict__ ntile_g,
             int* __restrict__ tte, int* __restrict__ ttm,
             int* __restrict__ tok, float* __restrict__ wgt)
{
    __shared__ int cnt[NSLICE][NEXP];
    __shared__ int off[NSLICE][NEXP];
    __shared__ int ebase[NEXP + 1];
    __shared__ int is64_s;
    int tid = threadIdx.x;
    int wv = tid >> 6, lane = tid & 63;

    if (wv == 0) {
        int bad = (te_raw[2 * lane + 1] != 0u);
        unsigned long long m = __ballot(bad);
        if (lane == 0) is64_s = (m == 0ull);
    }
    __syncthreads();
    int is64 = is64_s;

    int c[NEXP] = {0,0,0,0,0,0,0,0};
    int eids[4];
    #pragma unroll
    for (int it = 0; it < 4; ++it) {
        int p = wv * 256 + it * 64 + lane;
        int eid = is64 ? (int)te_raw[2*p] : (int)te_raw[p];
        eids[it] = eid;
        #pragma unroll
        for (int e = 0; e < NEXP; ++e) {
            unsigned long long m = __ballot(eid == e);
            c[e] += __popcll(m);
        }
    }
    if (lane == 0)
        #pragma unroll
        for (int e = 0; e < NEXP; ++e) cnt[wv][e] = c[e];
    __syncthreads();

    if (tid < NEXP) {
        int run = 0;
        for (int s = 0; s < NSLICE; ++s) { off[s][tid] = run; run += cnt[s][tid]; }
        ebase[tid] = run;
    }
    __syncthreads();
    if (tid == 0) {
        int s = 0;
        for (int e = 0; e < NEXP; ++e) { int t = ebase[e]; ebase[e] = s; expert_off[e] = s; s += t; }
        ebase[NEXP] = s; expert_off[NEXP] = s;
        int nt = 0;
        for (int e = 0; e < NEXP; ++e)
            for (int m = ebase[e]; m < ebase[e + 1]; m += 128) { tte[nt] = e; ttm[nt] = m; ++nt; }
        *ntile_g = nt;
    }
    __syncthreads();

    int roff[NEXP];
    #pragma unroll
    for (int e = 0; e < NEXP; ++e) roff[e] = ebase[e] + off[wv][e];
    #pragma unroll
    for (int it = 0; it < 4; ++it) {
        int p = wv * 256 + it * 64 + lane;
        int eid = eids[it];
        int dest = -1;
        #pragma unroll
        for (int e = 0; e < NEXP; ++e) {
            unsigned long long m = __ballot(eid == e);
            if (eid == e) dest = roff[e] + __popcll(m & ((1ull << lane) - 1ull));
            roff[e] += __popcll(m);
        }
        tok[dest] = p >> 1;
        wgt[dest] = top_w[p];
    }
}

// ---------------- gather x rows -> bf16 -------------------------------------
__global__ void gather_kernel(const float* __restrict__ x,
                              const int* __restrict__ tok,
                              bf16* __restrict__ Xg)
{
    int p = blockIdx.x;
    int t = tok[p];
    const float4* src = (const float4*)(x + (size_t)t * HID);
    float4 v = src[threadIdx.x];
    bf16x4 o;
    o[0] = (bf16)v.x; o[1] = (bf16)v.y; o[2] = (bf16)v.z; o[3] = (bf16)v.w;
    *(bf16x4*)(Xg + (size_t)p * HID + threadIdx.x * 4) = o;
}

// --------- transpose v5 (standalone, for the first bare group) --------------
__global__ void __launch_bounds__(256)
transpose_v5(const float* __restrict__ in1, bf16* __restrict__ out1,
             const float* __restrict__ in2, bf16* __restrict__ out2,
             int nz1, int R, int C)
{
    __shared__ u32 tile32[4][64 * 32];   // 32 KB
    int z = blockIdx.z;
    const float* in = (z < nz1) ? in1 : in2;
    bf16* o         = (z < nz1) ? out1 : out2;
    int e = (z < nz1) ? z : z - nz1;
    in += (size_t)e * R * C;
    o  += (size_t)e * R * C;
    int kt = blockIdx.x, nq = blockIdx.y;
    int k0 = kt * 64, c0 = nq * 256;
    int tid = threadIdx.x;
    int rbase = tid >> 6;
    int c4 = tid & 63;
    int grp = c4 >> 4, cq = c4 & 15;
    int fp0 = cq * 2;
    const float* base = in + (size_t)(k0 + rbase) * C + c0 + c4 * 4;
    f32x4v rb[16];
    #pragma unroll
    for (int it = 0; it < 16; ++it)
        rb[it] = __builtin_nontemporal_load((const f32x4v*)(base + (size_t)it * 4 * C));
    #pragma unroll
    for (int it = 0; it < 16; ++it) {
        int r = rbase + it * 4;
        union { bf16 h[2]; u32 w; } a, b;
        a.h[0] = (bf16)rb[it][0]; a.h[1] = (bf16)rb[it][1];
        b.h[0] = (bf16)rb[it][2]; b.h[1] = (bf16)rb[it][3];
        tile32[grp][r * 32 + (fp0       ^ (r & 31))] = a.w;
        tile32[grp][r * 32 + ((fp0 + 1) ^ (r & 31))] = b.w;
    }
    __syncthreads();
    int RT = R >> 6;
    #pragma unroll
    for (int it2 = 0; it2 < 8; ++it2) {
        int gg = it2 * 256 + tid;
        int group = gg >> 9, g = gg & 511;
        int f = g >> 3;
        int k8 = ((g & 7) ^ (f & 7)) * 8;
        union { bf16 h[8]; } pk;
        #pragma unroll
        for (int j = 0; j < 8; ++j) {
            u32 u = tile32[group][(k8 + j) * 32 + ((f >> 1) ^ ((k8 + j) & 31))];
            pk.h[j] = (f & 1) ? ((bf16*)&u)[1] : ((bf16*)&u)[0];
        }
        bf16* tbase = o + ((size_t)(nq * 4 + group) * RT + kt) * 4096;
        *(bf16x8*)(tbase + (size_t)g * 8) = *(bf16x8*)&pk;
    }
}

// ---------------- fused: ug-GEMM (XCD-swizzled) + generic v5 tr --------------
__global__ void __launch_bounds__(256)
fused_ug(const bf16* __restrict__ Xg,
         const bf16* __restrict__ wuT, const bf16* __restrict__ wgT,
         const int* __restrict__ expert_off, const int* __restrict__ ntile_g,
         const int* __restrict__ tte, const int* __restrict__ ttm,
         int eb, int gcnt, bf16* __restrict__ H1,
         const float* __restrict__ tin1, bf16* __restrict__ tout1,
         const float* __restrict__ tin2, bf16* __restrict__ tout2,
         int tnz1, int tR, int tC)
{
    __shared__ char ldsbuf[32768];
    int bid = blockIdx.x;
    int tid = threadIdx.x;

    if (bid >= NGEMM) {
        u32 (*tile32)[64 * 32] = (u32 (*)[64 * 32])ldsbuf;
        int tb = bid - NGEMM;
        int nkt = tR >> 6;
        int perslice = nkt * (tC >> 8);
        int z = tb / perslice, rem = tb - z * perslice;
        int kt = rem % nkt, nq = rem / nkt;
        const float* in; bf16* o; int e2;
        if (z < tnz1) { in = tin1; o = tout1; e2 = z; }
        else          { in = tin2; o = tout2; e2 = z - tnz1; }
        in += (size_t)e2 * tR * tC;
        o  += (size_t)e2 * tR * tC;
        int k0 = kt * 64, c0 = nq * 256;
        int rbase = tid >> 6;
        int c4 = tid & 63;
        int grp = c4 >> 4, cq = c4 & 15;
        int fp0 = cq * 2;
        const float* base = in + (size_t)(k0 + rbase) * tC + c0 + c4 * 4;
        f32x4v rb[16];
        #pragma unroll
        for (int it = 0; it < 16; ++it)
            rb[it] = __builtin_nontemporal_load((const f32x4v*)(base + (size_t)it * 4 * tC));
        #pragma unroll
        for (int it = 0; it < 16; ++it) {
            int r = rbase + it * 4;
            union { bf16 h[2]; u32 w; } a, b;
            a.h[0] = (bf16)rb[it][0]; a.h[1] = (bf16)rb[it][1];
            b.h[0] = (bf16)rb[it][2]; b.h[1] = (bf16)rb[it][3];
            tile32[grp][r * 32 + (fp0       ^ (r & 31))] = a.w;
            tile32[grp][r * 32 + ((fp0 + 1) ^ (r & 31))] = b.w;
        }
        __syncthreads();
        #pragma unroll
        for (int it2 = 0; it2 < 8; ++it2) {
            int gg = it2 * 256 + tid;
            int group = gg >> 9, g = gg & 511;
            int f = g >> 3;
            int k8 = ((g & 7) ^ (f & 7)) * 8;
            union { bf16 h[8]; } pk;
            #pragma unroll
            for (int j = 0; j < 8; ++j) {
                u32 u = tile32[group][(k8 + j) * 32 + ((f >> 1) ^ ((k8 + j) & 31))];
                pk.h[j] = (f & 1) ? ((bf16*)&u)[1] : ((bf16*)&u)[0];
            }
            bf16* tbase = o + ((size_t)(nq * 4 + group) * nkt + kt) * 4096;
            *(bf16x8*)(tbase + (size_t)g * 8) = *(bf16x8*)&pk;
        }
        return;
    }

    int ty, bn;
    xcd_decode(bid, 32, ty, bn);     // all 32 N-blocks of a ty share an XCD
    if (ty >= *ntile_g) return;
    int e = tte[ty];
    if (e < eb || e >= eb + gcnt) return;
    int m0 = ttm[ty];
    int p1 = expert_off[e + 1];
    int n0 = bn * 64;
    bf16* As  = (bf16*)ldsbuf;
    bf16* Bus = (bf16*)(ldsbuf + 16384);
    bf16* Bgs = (bf16*)(ldsbuf + 24576);
    int lane = tid & 63, wv = tid >> 6;
    int wm = wv >> 1, wn = wv & 1;
    int l16 = lane & 15, lhi = lane >> 4;
    f32x4 accU[4][2] = {};
    f32x4 accG[4][2] = {};

    const bf16* aptr[4]; u32 alds[4];
    #pragma unroll
    for (int c = 0; c < 4; ++c) {
        int g = c * 256 + tid;
        int r = g >> 3, pos = g & 7;
        int gr = m0 + r; if (gr >= p1) gr = p1 - 1;
        int gsrc = pos ^ (r & 7);
        aptr[c] = Xg + (size_t)gr * HID + gsrc * 8;
        alds[c] = g * 16;
    }
    size_t tb0 = (size_t)e * EXPELEM + (size_t)(n0 >> 6) * (HID >> 6) * 4096;
    const bf16* buptr[2]; const bf16* bgptr[2]; u32 blds[2];
    #pragma unroll
    for (int c = 0; c < 2; ++c) {
        int g = c * 256 + tid;
        buptr[c] = wuT + tb0 + (size_t)g * 8;
        bgptr[c] = wgT + tb0 + (size_t)g * 8;
        blds[c] = g * 16;
    }
    u32 aro[2][4], bro[2][2];
    #pragma unroll
    for (int ks = 0; ks < 2; ++ks) {
        #pragma unroll
        for (int fm = 0; fm < 4; ++fm) {
            int r = wm * 64 + fm * 16 + l16;
            aro[ks][fm] = r * 128 + ((u32)((ks * 4 + lhi) ^ (r & 7))) * 16;
        }
        #pragma unroll
        for (int fn = 0; fn < 2; ++fn) {
            int fr = wn * 32 + fn * 16 + l16;
            bro[ks][fn] = fr * 128 + ((u32)((ks * 4 + lhi) ^ (fr & 7))) * 16;
        }
    }

    for (int t = 0; t < HID / 64; ++t) {
        #pragma unroll
        for (int c = 0; c < 4; ++c) { gld16(aptr[c], (char*)As + alds[c]); aptr[c] += 64; }
        #pragma unroll
        for (int c = 0; c < 2; ++c) {
            gld16(buptr[c], (char*)Bus + blds[c]); buptr[c] += 4096;
            gld16(bgptr[c], (char*)Bgs + blds[c]); bgptr[c] += 4096;
        }
        __syncthreads();
        #pragma unroll
        for (int ks = 0; ks < 2; ++ks) {
            bf16x8 af[4];
            #pragma unroll
            for (int fm = 0; fm < 4; ++fm)
                af[fm] = *(const bf16x8*)((char*)As + aro[ks][fm]);
            #pragma unroll
            for (int fn = 0; fn < 2; ++fn) {
                bf16x8 bu = *(const bf16x8*)((char*)Bus + bro[ks][fn]);
                bf16x8 bg = *(const bf16x8*)((char*)Bgs + bro[ks][fn]);
                #pragma unroll
                for (int fm = 0; fm < 4; ++fm) {
                    accU[fm][fn] = __builtin_amdgcn_mfma_f32_16x16x32_bf16(af[fm], bu, accU[fm][fn], 0, 0, 0);
                    accG[fm][fn] = __builtin_amdgcn_mfma_f32_16x16x32_bf16(af[fm], bg, accG[fm][fn], 0, 0, 0);
                }
            }
        }
        __syncthreads();
    }
    #pragma unroll
    for (int fm = 0; fm < 4; ++fm)
    #pragma unroll
    for (int fn = 0; fn < 2; ++fn)
    #pragma unroll
    for (int rg = 0; rg < 4; ++rg) {
        int r = m0 + wm * 64 + fm * 16 + lhi * 4 + rg;
        if (r < p1) {
            float u = accU[fm][fn][rg], g = accG[fm][fn][rg];
            float h = (u / (1.f + __expf(-u))) * g;
            int fc = n0 + wn * 32 + fn * 16 + l16;
            H1[(size_t)r * FFN_ + fc] = (bf16)h;
        }
    }
}

// ---------------- GEMM2 (image weights, R19 body, XCD-swizzled grid) --------
__global__ void __launch_bounds__(256)
moe_down(const bf16* __restrict__ H1, const bf16* __restrict__ wdT,
         const int* __restrict__ expert_off, const int* __restrict__ ntile_g,
         const int* __restrict__ tte, const int* __restrict__ ttm,
         const int* __restrict__ tok, const float* __restrict__ wgt,
         float* __restrict__ out)
{
    int ty, bn;
    xcd_decode(blockIdx.x, 16, ty, bn);  // 16 N-blocks of a ty share an XCD
    if (ty >= *ntile_g) return;
    int e = tte[ty];
    int m0 = ttm[ty];
    int p1 = expert_off[e + 1];
    int n0 = bn * 64;
    __shared__ bf16 As[128 * 64];
    __shared__ bf16 Bs [64 * 64];
    __shared__ float wgt_s[128];
    __shared__ int   tok_s[128];
    int tid = threadIdx.x, lane = tid & 63, wv = tid >> 6;
    int wm = wv >> 1, wn = wv & 1;
    int l16 = lane & 15, lhi = lane >> 4;
    if (tid < 128) {
        int r = m0 + tid;
        if (r < p1) { wgt_s[tid] = wgt[r]; tok_s[tid] = tok[r]; }
        else        { wgt_s[tid] = 0.f;    tok_s[tid] = 0; }
    }
    f32x4 acc[4][2] = {};

    const bf16* aptr[4]; u32 alds[4];
    #pragma unroll
    for (int c = 0; c < 4; ++c) {
        int g = c * 256 + tid;
        int r = g >> 3, pos = g & 7;
        int gr = m0 + r; if (gr >= p1) gr = p1 - 1;
        int gsrc = pos ^ (r & 7);
        aptr[c] = H1 + (size_t)gr * FFN_ + gsrc * 8;
        alds[c] = g * 16;
    }
    size_t tb0 = (size_t)e * EXPELEM + (size_t)(n0 >> 6) * (FFN_ >> 6) * 4096;
    const bf16* bptr[2]; u32 blds[2];
    #pragma unroll
    for (int c = 0; c < 2; ++c) {
        int g = c * 256 + tid;
        bptr[c] = wdT + tb0 + (size_t)g * 8;
        blds[c] = g * 16;
    }
    u32 aro[2][4], bro[2][2];
    #pragma unroll
    for (int ks = 0; ks < 2; ++ks) {
        #pragma unroll
        for (int fm = 0; fm < 4; ++fm) {
            int r = wm * 64 + fm * 16 + l16;
            aro[ks][fm] = r * 128 + ((u32)((ks * 4 + lhi) ^ (r & 7))) * 16;
        }
        #pragma unroll
        for (int fn = 0; fn < 2; ++fn) {
            int fr = wn * 32 + fn * 16 + l16;
            bro[ks][fn] = fr * 128 + ((u32)((ks * 4 + lhi) ^ (fr & 7))) * 16;
        }
    }

    for (int t = 0; t < FFN_ / 64; ++t) {
        #pragma unroll
        for (int c = 0; c < 4; ++c) { gld16(aptr[c], (char*)As + alds[c]); aptr[c] += 64; }
        #pragma unroll
        for (int c = 0; c < 2; ++c) { gld16(bptr[c], (char*)Bs + blds[c]); bptr[c] += 4096; }
        __syncthreads();
        #pragma unroll
        for (int ks = 0; ks < 2; ++ks) {
            bf16x8 af[4];
            #pragma unroll
            for (int fm = 0; fm < 4; ++fm)
                af[fm] = *(const bf16x8*)((char*)As + aro[ks][fm]);
            #pragma unroll
            for (int fn = 0; fn < 2; ++fn) {
                bf16x8 bd = *(const bf16x8*)((char*)Bs + bro[ks][fn]);
                #pragma unroll
                for (int fm = 0; fm < 4; ++fm)
                    acc[fm][fn] = __builtin_amdgcn_mfma_f32_16x16x32_bf16(af[fm], bd, acc[fm][fn], 0, 0, 0);
            }
        }
        __syncthreads();
    }
    #pragma unroll
    for (int fm = 0; fm < 4; ++fm)
    #pragma unroll
    for (int fn = 0; fn < 2; ++fn)
    #pragma unroll
    for (int rg = 0; rg < 4; ++rg) {
        int rl = wm * 64 + fm * 16 + lhi * 4 + rg;
        if (m0 + rl < p1) {
            float v = acc[fm][fn][rg] * wgt_s[rl];
            atomicAdd(out + (size_t)tok_s[rl] * HID + n0 + wn * 32 + fn * 16 + l16, v);
        }
    }
}

extern "C" void kernel_launch(void* const* d_in, const int* in_sizes, int n_in,
                              void* d_out, int out_size, void* d_ws, size_t ws_size,
                              hipStream_t stream)
{
    const float*    x      = (const float*)d_in[0];
    const float*    top_w  = (const float*)d_in[2];
    const uint32_t* te     = (const uint32_t*)d_in[3];
    const float*    w_up   = (const float*)d_in[4];
    const float*    w_gate = (const float*)d_in[5];
    const float*    w_down = (const float*)d_in[6];
    float* out = (float*)d_out;
    char*  ws  = (char*)d_ws;

    int*   expert_off = (int*)(ws + OFF_EXP);
    int*   ntile_g    = (int*)(ws + OFF_NT);
    int*   tte        = (int*)(ws + OFF_TTE);
    int*   ttm        = (int*)(ws + OFF_TTM);
    int*   tok        = (int*)(ws + OFF_TOK);
    float* wgt        = (float*)(ws + OFF_WGT);
    bf16*  Xg         = (bf16*)(ws + OFF_XG);
    bf16*  H1         = (bf16*)(ws + OFF_H1);
    bf16*  WT         = (bf16*)(ws + OFF_WT);
    bf16*  wuT = WT;
    bf16*  wgT = WT + 8 * EXPELEM;     // +32 MB
    bf16*  wdT = WT + 16 * EXPELEM;    // +64 MB

    hipMemsetAsync(out, 0, (size_t)out_size * sizeof(float), stream);
    hipLaunchKernelGGL(route_kernel, dim3(1), dim3(1024), 0, stream,
                       te, top_w, expert_off, ntile_g, tte, ttm, tok, wgt);
    hipLaunchKernelGGL(gather_kernel, dim3(NPAIR), dim3(256), 0, stream,
                       x, tok, Xg);

    // L2: bare transpose of up/gate experts 0-3
    hipLaunchKernelGGL(transpose_v5, dim3(HID / 64, FFN_ / 256, 8), dim3(256), 0, stream,
                       w_up, wuT, w_gate, wgT, 4, HID, FFN_);

    // L3: ug GEMM experts 0-3  ||  transpose up/gate experts 4-7
    hipLaunchKernelGGL(fused_ug, dim3(NGEMM + 1024), dim3(256), 0, stream,
                       Xg, wuT, wgT, expert_off, ntile_g, tte, ttm, 0, 4, H1,
                       w_up + 4 * EXPELEM, wuT + 4 * EXPELEM,
                       w_gate + 4 * EXPELEM, wgT + 4 * EXPELEM, 4, HID, FFN_);

    // L4: ug GEMM experts 4-7  ||  transpose w_down all experts
    hipLaunchKernelGGL(fused_ug, dim3(NGEMM + 1024), dim3(256), 0, stream,
                       Xg, wuT, wgT, expert_off, ntile_g, tte, ttm, 4, 4, H1,
                       w_down, wdT, w_down, wdT, 8, FFN_, HID);

    // L5: down GEMM (128x64, XCD-swizzled grid)
    hipLaunchKernelGGL(moe_down, dim3(NDOWN), dim3(256), 0, stream,
                       H1, wdT, expert_off, ntile_g, tte, ttm, tok, wgt, out);
}

// Round 23
// 157.200 us; speedup vs baseline: 1.1327x; 1.1327x over previous
//
#include <hip/hip_runtime.h>
#include <hip/hip_bf16.h>
#include <stdint.h>

#define T_TOK 2048
#define HID   1024
#define FFN_  2048
#define NEXP  8
#define NPAIR 4096   // T_TOK * top_k(2)
#define MAXTILE 40   // sum over experts of ceil(cnt/128) <= 32+8
#define EXPELEM ((size_t)HID * FFN_)
#define NSLICE 16    // route slices (waves)
#define NGEMM (MAXTILE * (FFN_ / 64))   // 1280

typedef __bf16 bf16;
typedef __bf16 bf16x8 __attribute__((ext_vector_type(8)));
typedef __bf16 bf16x4 __attribute__((ext_vector_type(4)));
typedef float  f32x4  __attribute__((ext_vector_type(4)));
typedef float  f32x4v __attribute__((ext_vector_type(4)));
typedef unsigned int u32;

// ---- workspace layout (bytes) ----
#define OFF_EXP   0
#define OFF_NT    64
#define OFF_TTE   128
#define OFF_TTM   512
#define OFF_TOK   1024
#define OFF_WGT   (OFF_TOK + 16384)
#define OFF_XG    65536
#define OFF_H1    (OFF_XG + (size_t)NPAIR*HID*2)
#define OFF_WT    (OFF_H1 + (size_t)NPAIR*FFN_*2)   // [wuT 32M][wgT 32M][wdT 32M]

__device__ __forceinline__ void gld16(const void* g, void* l) {
    __builtin_amdgcn_global_load_lds(
        (const __attribute__((address_space(1))) u32*)g,
        (__attribute__((address_space(3))) u32*)l, 16, 0, 0);
}

// ---------------- routing: two-level parallel counting sort -----------------
__global__ void __launch_bounds__(1024)
route_kernel(const uint32_t* __restrict__ te_raw,
             const float* __restrict__ top_w,
             int* __restrict__ expert_off,
             int* __restrict__ ntile_g,
             int* __restrict__ tte, int* __restrict__ ttm,
             int* __restrict__ tok, float* __restrict__ wgt)
{
    __shared__ int cnt[NSLICE][NEXP];
    __shared__ int off[NSLICE][NEXP];
    __shared__ int ebase[NEXP + 1];
    __shared__ int is64_s;
    int tid = threadIdx.x;
    int wv = tid >> 6, lane = tid & 63;

    if (wv == 0) {
        int bad = (te_raw[2 * lane + 1] != 0u);
        unsigned long long m = __ballot(bad);
        if (lane == 0) is64_s = (m == 0ull);
    }
    __syncthreads();
    int is64 = is64_s;

    int c[NEXP] = {0,0,0,0,0,0,0,0};
    int eids[4];
    #pragma unroll
    for (int it = 0; it < 4; ++it) {
        int p = wv * 256 + it * 64 + lane;
        int eid = is64 ? (int)te_raw[2*p] : (int)te_raw[p];
        eids[it] = eid;
        #pragma unroll
        for (int e = 0; e < NEXP; ++e) {
            unsigned long long m = __ballot(eid == e);
            c[e] += __popcll(m);
        }
    }
    if (lane == 0)
        #pragma unroll
        for (int e = 0; e < NEXP; ++e) cnt[wv][e] = c[e];
    __syncthreads();

    if (tid < NEXP) {
        int run = 0;
        for (int s = 0; s < NSLICE; ++s) { off[s][tid] = run; run += cnt[s][tid]; }
        ebase[tid] = run;
    }
    __syncthreads();
    if (tid == 0) {
        int s = 0;
        for (int e = 0; e < NEXP; ++e) { int t = ebase[e]; ebase[e] = s; expert_off[e] = s; s += t; }
        ebase[NEXP] = s; expert_off[NEXP] = s;
        int nt = 0;
        for (int e = 0; e < NEXP; ++e)
            for (int m = ebase[e]; m < ebase[e + 1]; m += 128) { tte[nt] = e; ttm[nt] = m; ++nt; }
        *ntile_g = nt;
    }
    __syncthreads();

    int roff[NEXP];
    #pragma unroll
    for (int e = 0; e < NEXP; ++e) roff[e] = ebase[e] + off[wv][e];
    #pragma unroll
    for (int it = 0; it < 4; ++it) {
        int p = wv * 256 + it * 64 + lane;
        int eid = eids[it];
        int dest = -1;
        #pragma unroll
        for (int e = 0; e < NEXP; ++e) {
            unsigned long long m = __ballot(eid == e);
            if (eid == e) dest = roff[e] + __popcll(m & ((1ull << lane) - 1ull));
            roff[e] += __popcll(m);
        }
        tok[dest] = p >> 1;
        wgt[dest] = top_w[p];
    }
}

// ---------------- gather x rows -> bf16 -------------------------------------
__global__ void gather_kernel(const float* __restrict__ x,
                              const int* __restrict__ tok,
                              bf16* __restrict__ Xg)
{
    int p = blockIdx.x;
    int t = tok[p];
    const float4* src = (const float4*)(x + (size_t)t * HID);
    float4 v = src[threadIdx.x];
    bf16x4 o;
    o[0] = (bf16)v.x; o[1] = (bf16)v.y; o[2] = (bf16)v.z; o[3] = (bf16)v.w;
    *(bf16x4*)(Xg + (size_t)p * HID + threadIdx.x * 4) = o;
}

// --------- transpose v5: f32 [R][C] -> tile-image bf16, MLP+NT reads --------
__global__ void __launch_bounds__(256)
transpose_v5(const float* __restrict__ in1, bf16* __restrict__ out1,
             const float* __restrict__ in2, bf16* __restrict__ out2,
             int nz1, int R, int C)
{
    __shared__ u32 tile32[4][64 * 32];   // 32 KB
    int z = blockIdx.z;
    const float* in = (z < nz1) ? in1 : in2;
    bf16* o         = (z < nz1) ? out1 : out2;
    int e = (z < nz1) ? z : z - nz1;
    in += (size_t)e * R * C;
    o  += (size_t)e * R * C;
    int kt = blockIdx.x, nq = blockIdx.y;
    int k0 = kt * 64, c0 = nq * 256;
    int tid = threadIdx.x;
    int rbase = tid >> 6;
    int c4 = tid & 63;
    int grp = c4 >> 4, cq = c4 & 15;
    int fp0 = cq * 2;
    const float* base = in + (size_t)(k0 + rbase) * C + c0 + c4 * 4;
    f32x4v rb[16];
    #pragma unroll
    for (int it = 0; it < 16; ++it)
        rb[it] = __builtin_nontemporal_load((const f32x4v*)(base + (size_t)it * 4 * C));
    #pragma unroll
    for (int it = 0; it < 16; ++it) {
        int r = rbase + it * 4;
        union { bf16 h[2]; u32 w; } a, b;
        a.h[0] = (bf16)rb[it][0]; a.h[1] = (bf16)rb[it][1];
        b.h[0] = (bf16)rb[it][2]; b.h[1] = (bf16)rb[it][3];
        tile32[grp][r * 32 + (fp0       ^ (r & 31))] = a.w;
        tile32[grp][r * 32 + ((fp0 + 1) ^ (r & 31))] = b.w;
    }
    __syncthreads();
    int RT = R >> 6;
    #pragma unroll
    for (int it2 = 0; it2 < 8; ++it2) {
        int gg = it2 * 256 + tid;
        int group = gg >> 9, g = gg & 511;
        int f = g >> 3;
        int k8 = ((g & 7) ^ (f & 7)) * 8;
        union { bf16 h[8]; } pk;
        #pragma unroll
        for (int j = 0; j < 8; ++j) {
            u32 u = tile32[group][(k8 + j) * 32 + ((f >> 1) ^ ((k8 + j) & 31))];
            pk.h[j] = (f & 1) ? ((bf16*)&u)[1] : ((bf16*)&u)[0];
        }
        bf16* tbase = o + ((size_t)(nq * 4 + group) * RT + kt) * 4096;
        *(bf16x8*)(tbase + (size_t)g * 8) = *(bf16x8*)&pk;
    }
}

// ---------------- fused: ug-GEMM blocks + w_down transpose blocks (R18) -----
__global__ void __launch_bounds__(256)
fused_ug(const bf16* __restrict__ Xg,
         const bf16* __restrict__ wuT, const bf16* __restrict__ wgT,
         const int* __restrict__ expert_off, const int* __restrict__ ntile_g,
         const int* __restrict__ tte, const int* __restrict__ ttm,
         bf16* __restrict__ H1,
         const float* __restrict__ Wd, bf16* __restrict__ wdT)
{
    __shared__ char ldsbuf[32768];
    int bid = blockIdx.x;
    int tid = threadIdx.x;

    if (bid >= NGEMM) {
        // ---------- transpose path: w_down f32 [FFN_][HID] -> images ----------
        u32 (*tile32)[64 * 32] = (u32 (*)[64 * 32])ldsbuf;
        int tb = bid - NGEMM;            // 0..1023
        int e = tb >> 7;                 // 128 blocks/expert (32 kt x 4 nq)
        int rem = tb & 127;
        int nq = rem >> 5, kt = rem & 31;
        const float* in = Wd + (size_t)e * EXPELEM;
        bf16* o = wdT + (size_t)e * EXPELEM;
        int k0 = kt * 64, c0 = nq * 256;
        int rbase = tid >> 6;
        int c4 = tid & 63;
        int grp = c4 >> 4, cq = c4 & 15;
        int fp0 = cq * 2;
        const float* base = in + (size_t)(k0 + rbase) * HID + c0 + c4 * 4;
        f32x4v rb[16];
        #pragma unroll
        for (int it = 0; it < 16; ++it)
            rb[it] = __builtin_nontemporal_load((const f32x4v*)(base + (size_t)it * 4 * HID));
        #pragma unroll
        for (int it = 0; it < 16; ++it) {
            int r = rbase + it * 4;
            union { bf16 h[2]; u32 w; } a, b;
            a.h[0] = (bf16)rb[it][0]; a.h[1] = (bf16)rb[it][1];
            b.h[0] = (bf16)rb[it][2]; b.h[1] = (bf16)rb[it][3];
            tile32[grp][r * 32 + (fp0       ^ (r & 31))] = a.w;
            tile32[grp][r * 32 + ((fp0 + 1) ^ (r & 31))] = b.w;
        }
        __syncthreads();
        const int RT = FFN_ >> 6;        // 32
        #pragma unroll
        for (int it2 = 0; it2 < 8; ++it2) {
            int gg = it2 * 256 + tid;
            int group = gg >> 9, g = gg & 511;
            int f = g >> 3;
            int k8 = ((g & 7) ^ (f & 7)) * 8;
            union { bf16 h[8]; } pk;
            #pragma unroll
            for (int j = 0; j < 8; ++j) {
                u32 u = tile32[group][(k8 + j) * 32 + ((f >> 1) ^ ((k8 + j) & 31))];
                pk.h[j] = (f & 1) ? ((bf16*)&u)[1] : ((bf16*)&u)[0];
            }
            bf16* tbase = o + ((size_t)(nq * 4 + group) * RT + kt) * 4096;
            *(bf16x8*)(tbase + (size_t)g * 8) = *(bf16x8*)&pk;
        }
        return;
    }

    // ---------- ug GEMM path (R18-verified body) ----------
    int ty = bid >> 5, bn = bid & 31;
    if (ty >= *ntile_g) return;
    int e = tte[ty];
    int m0 = ttm[ty];
    int p1 = expert_off[e + 1];
    int n0 = bn * 64;
    bf16* As  = (bf16*)ldsbuf;
    bf16* Bus = (bf16*)(ldsbuf + 16384);
    bf16* Bgs = (bf16*)(ldsbuf + 24576);
    int lane = tid & 63, wv = tid >> 6;
    int wm = wv >> 1, wn = wv & 1;
    int l16 = lane & 15, lhi = lane >> 4;
    f32x4 accU[4][2] = {};
    f32x4 accG[4][2] = {};

    const bf16* aptr[4]; u32 alds[4];
    #pragma unroll
    for (int c = 0; c < 4; ++c) {
        int g = c * 256 + tid;
        int r = g >> 3, pos = g & 7;
        int gr = m0 + r; if (gr >= p1) gr = p1 - 1;
        int gsrc = pos ^ (r & 7);
        aptr[c] = Xg + (size_t)gr * HID + gsrc * 8;
        alds[c] = g * 16;
    }
    size_t tb0 = (size_t)e * EXPELEM + (size_t)(n0 >> 6) * (HID >> 6) * 4096;
    const bf16* buptr[2]; const bf16* bgptr[2]; u32 blds[2];
    #pragma unroll
    for (int c = 0; c < 2; ++c) {
        int g = c * 256 + tid;
        buptr[c] = wuT + tb0 + (size_t)g * 8;
        bgptr[c] = wgT + tb0 + (size_t)g * 8;
        blds[c] = g * 16;
    }
    u32 aro[2][4], bro[2][2];
    #pragma unroll
    for (int ks = 0; ks < 2; ++ks) {
        #pragma unroll
        for (int fm = 0; fm < 4; ++fm) {
            int r = wm * 64 + fm * 16 + l16;
            aro[ks][fm] = r * 128 + ((u32)((ks * 4 + lhi) ^ (r & 7))) * 16;
        }
        #pragma unroll
        for (int fn = 0; fn < 2; ++fn) {
            int fr = wn * 32 + fn * 16 + l16;
            bro[ks][fn] = fr * 128 + ((u32)((ks * 4 + lhi) ^ (fr & 7))) * 16;
        }
    }

    for (int t = 0; t < HID / 64; ++t) {
        #pragma unroll
        for (int c = 0; c < 4; ++c) { gld16(aptr[c], (char*)As + alds[c]); aptr[c] += 64; }
        #pragma unroll
        for (int c = 0; c < 2; ++c) {
            gld16(buptr[c], (char*)Bus + blds[c]); buptr[c] += 4096;
            gld16(bgptr[c], (char*)Bgs + blds[c]); bgptr[c] += 4096;
        }
        __syncthreads();
        #pragma unroll
        for (int ks = 0; ks < 2; ++ks) {
            bf16x8 af[4];
            #pragma unroll
            for (int fm = 0; fm < 4; ++fm)
                af[fm] = *(const bf16x8*)((char*)As + aro[ks][fm]);
            #pragma unroll
            for (int fn = 0; fn < 2; ++fn) {
                bf16x8 bu = *(const bf16x8*)((char*)Bus + bro[ks][fn]);
                bf16x8 bg = *(const bf16x8*)((char*)Bgs + bro[ks][fn]);
                #pragma unroll
                for (int fm = 0; fm < 4; ++fm) {
                    accU[fm][fn] = __builtin_amdgcn_mfma_f32_16x16x32_bf16(af[fm], bu, accU[fm][fn], 0, 0, 0);
                    accG[fm][fn] = __builtin_amdgcn_mfma_f32_16x16x32_bf16(af[fm], bg, accG[fm][fn], 0, 0, 0);
                }
            }
        }
        __syncthreads();
    }
    #pragma unroll
    for (int fm = 0; fm < 4; ++fm)
    #pragma unroll
    for (int fn = 0; fn < 2; ++fn)
    #pragma unroll
    for (int rg = 0; rg < 4; ++rg) {
        int r = m0 + wm * 64 + fm * 16 + lhi * 4 + rg;
        if (r < p1) {
            float u = accU[fm][fn][rg], g = accG[fm][fn][rg];
            float h = (u / (1.f + __expf(-u))) * g;
            int fc = n0 + wn * 32 + fn * 16 + l16;
            H1[(size_t)r * FFN_ + fc] = (bf16)h;
        }
    }
}

// ---------------- GEMM2: 128(M) x 128(N) tiles — A re-read traffic halved ---
// 4 waves as 2x2, each wave 64x64 out; B = two stacked 64-row images (16 KB).
__global__ void __launch_bounds__(256)
moe_down(const bf16* __restrict__ H1, const bf16* __restrict__ wdT,
         const int* __restrict__ expert_off, const int* __restrict__ ntile_g,
         const int* __restrict__ tte, const int* __restrict__ ttm,
         const int* __restrict__ tok, const float* __restrict__ wgt,
         float* __restrict__ out)
{
    int ty = blockIdx.y;
    if (ty >= *ntile_g) return;
    int e = tte[ty];
    int m0 = ttm[ty];
    int p1 = expert_off[e + 1];
    int n0 = blockIdx.x * 128;
    __shared__ bf16 As[128 * 64];    // 16 KB
    __shared__ bf16 Bs[128 * 64];    // 16 KB (rows 0-63: image 2bn, 64-127: 2bn+1)
    __shared__ float wgt_s[128];
    __shared__ int   tok_s[128];
    int tid = threadIdx.x, lane = tid & 63, wv = tid >> 6;
    int wm = wv >> 1, wn = wv & 1;
    int l16 = lane & 15, lhi = lane >> 4;
    if (tid < 128) {
        int r = m0 + tid;
        if (r < p1) { wgt_s[tid] = wgt[r]; tok_s[tid] = tok[r]; }
        else        { wgt_s[tid] = 0.f;    tok_s[tid] = 0; }
    }
    f32x4 acc[4][4] = {};

    const bf16* aptr[4]; u32 alds[4];
    #pragma unroll
    for (int c = 0; c < 4; ++c) {
        int g = c * 256 + tid;
        int r = g >> 3, pos = g & 7;
        int gr = m0 + r; if (gr >= p1) gr = p1 - 1;
        int gsrc = pos ^ (r & 7);
        aptr[c] = H1 + (size_t)gr * FFN_ + gsrc * 8;
        alds[c] = g * 16;
    }
    // B: granule g in [0,1024): image = g>>9 (n-tile 2bn+image), gi = g&511
    const bf16* bptr[4]; u32 blds[4];
    #pragma unroll
    for (int c = 0; c < 4; ++c) {
        int g = c * 256 + tid;
        int img = g >> 9, gi = g & 511;
        bptr[c] = wdT + (size_t)e * EXPELEM
                + (size_t)((n0 >> 6) + img) * (FFN_ >> 6) * 4096
                + (size_t)gi * 8;
        blds[c] = (u32)img * 8192 + (u32)gi * 16;
    }
    u32 aro[2][4], bro[2][4];
    #pragma unroll
    for (int ks = 0; ks < 2; ++ks) {
        #pragma unroll
        for (int fm = 0; fm < 4; ++fm) {
            int r = wm * 64 + fm * 16 + l16;
            aro[ks][fm] = r * 128 + ((u32)((ks * 4 + lhi) ^ (r & 7))) * 16;
        }
        #pragma unroll
        for (int fn = 0; fn < 4; ++fn) {
            int fr = wn * 64 + fn * 16 + l16;
            bro[ks][fn] = fr * 128 + ((u32)((ks * 4 + lhi) ^ (fr & 7))) * 16;
        }
    }

    for (int t = 0; t < FFN_ / 64; ++t) {
        #pragma unroll
        for (int c = 0; c < 4; ++c) { gld16(aptr[c], (char*)As + alds[c]); aptr[c] += 64; }
        #pragma unroll
        for (int c = 0; c < 4; ++c) { gld16(bptr[c], (char*)Bs + blds[c]); bptr[c] += 4096; }
        __syncthreads();
        #pragma unroll
        for (int ks = 0; ks < 2; ++ks) {
            bf16x8 af[4];
            #pragma unroll
            for (int fm = 0; fm < 4; ++fm)
                af[fm] = *(const bf16x8*)((char*)As + aro[ks][fm]);
            #pragma unroll
            for (int fn = 0; fn < 4; ++fn) {
                bf16x8 bd = *(const bf16x8*)((char*)Bs + bro[ks][fn]);
                #pragma unroll
                for (int fm = 0; fm < 4; ++fm)
                    acc[fm][fn] = __builtin_amdgcn_mfma_f32_16x16x32_bf16(af[fm], bd, acc[fm][fn], 0, 0, 0);
            }
        }
        __syncthreads();
    }
    #pragma unroll
    for (int fm = 0; fm < 4; ++fm)
    #pragma unroll
    for (int fn = 0; fn < 4; ++fn)
    #pragma unroll
    for (int rg = 0; rg < 4; ++rg) {
        int rl = wm * 64 + fm * 16 + lhi * 4 + rg;
        if (m0 + rl < p1) {
            float v = acc[fm][fn][rg] * wgt_s[rl];
            atomicAdd(out + (size_t)tok_s[rl] * HID + n0 + wn * 64 + fn * 16 + l16, v);
        }
    }
}

extern "C" void kernel_launch(void* const* d_in, const int* in_sizes, int n_in,
                              void* d_out, int out_size, void* d_ws, size_t ws_size,
                              hipStream_t stream)
{
    const float*    x      = (const float*)d_in[0];
    const float*    top_w  = (const float*)d_in[2];
    const uint32_t* te     = (const uint32_t*)d_in[3];
    const float*    w_up   = (const float*)d_in[4];
    const float*    w_gate = (const float*)d_in[5];
    const float*    w_down = (const float*)d_in[6];
    float* out = (float*)d_out;
    char*  ws  = (char*)d_ws;

    int*   expert_off = (int*)(ws + OFF_EXP);
    int*   ntile_g    = (int*)(ws + OFF_NT);
    int*   tte        = (int*)(ws + OFF_TTE);
    int*   ttm        = (int*)(ws + OFF_TTM);
    int*   tok        = (int*)(ws + OFF_TOK);
    float* wgt        = (float*)(ws + OFF_WGT);
    bf16*  Xg         = (bf16*)(ws + OFF_XG);
    bf16*  H1         = (bf16*)(ws + OFF_H1);
    bf16*  WT         = (bf16*)(ws + OFF_WT);
    bf16*  wuT = WT;
    bf16*  wgT = WT + 8 * EXPELEM;     // +32 MB
    bf16*  wdT = WT + 16 * EXPELEM;    // +64 MB

    hipMemsetAsync(out, 0, (size_t)out_size * sizeof(float), stream);
    hipLaunchKernelGGL(route_kernel, dim3(1), dim3(1024), 0, stream,
                       te, top_w, expert_off, ntile_g, tte, ttm, tok, wgt);
    hipLaunchKernelGGL(gather_kernel, dim3(NPAIR), dim3(256), 0, stream,
                       x, tok, Xg);

    // up/gate weight conversion (v5)
    hipLaunchKernelGGL(transpose_v5, dim3(HID / 64, FFN_ / 256, 16), dim3(256), 0, stream,
                       w_up, wuT, w_gate, wgT, 8, HID, FFN_);

    // fused: ug GEMM (1280 blocks) + w_down transpose (1024 blocks)
    hipLaunchKernelGGL(fused_ug, dim3(NGEMM + 1024), dim3(256), 0, stream,
                       Xg, wuT, wgT, expert_off, ntile_g, tte, ttm, H1,
                       w_down, wdT);

    // down GEMM: 128x128 tiles (8 x 40 = 320 blocks)
    hipLaunchKernelGGL(moe_down, dim3(HID / 128, MAXTILE), dim3(256), 0, stream,
                       H1, wdT, expert_off, ntile_g, tte, ttm, tok, wgt, out);
}

// Round 24
// 153.926 us; speedup vs baseline: 1.1568x; 1.0213x over previous
//
#include <hip/hip_runtime.h>
#include <hip/hip_bf16.h>
#include <stdint.h>

#define T_TOK 2048
#define HID   1024
#define FFN_  2048
#define NEXP  8
#define NPAIR 4096   // T_TOK * top_k(2)
#define MAXTILE 40   // sum over experts of ceil(cnt/128) <= 32+8
#define EXPELEM ((size_t)HID * FFN_)
#define NSLICE 16    // route slices (waves)
#define NGEMM (MAXTILE * (FFN_ / 64))   // 1280

typedef __bf16 bf16;
typedef __bf16 bf16x8 __attribute__((ext_vector_type(8)));
typedef __bf16 bf16x4 __attribute__((ext_vector_type(4)));
typedef float  f32x4  __attribute__((ext_vector_type(4)));
typedef float  f32x4v __attribute__((ext_vector_type(4)));
typedef unsigned int u32;

// ---- workspace layout (bytes) ----
#define OFF_EXP   0
#define OFF_NT    64
#define OFF_TTE   128
#define OFF_TTM   512
#define OFF_TOK   1024
#define OFF_WGT   (OFF_TOK + 16384)
#define OFF_XG    65536
#define OFF_H1    (OFF_XG + (size_t)NPAIR*HID*2)
#define OFF_WT    (OFF_H1 + (size_t)NPAIR*FFN_*2)   // [wuT 32M][wgT 32M][wdT 32M]

__device__ __forceinline__ void gld16(const void* g, void* l) {
    __builtin_amdgcn_global_load_lds(
        (const __attribute__((address_space(1))) u32*)g,
        (__attribute__((address_space(3))) u32*)l, 16, 0, 0);
}

// ---------------- routing: two-level parallel counting sort -----------------
__global__ void __launch_bounds__(1024)
route_kernel(const uint32_t* __restrict__ te_raw,
             const float* __restrict__ top_w,
             int* __restrict__ expert_off,
             int* __restrict__ ntile_g,
             int* __restrict__ tte, int* __restrict__ ttm,
             int* __restrict__ tok, float* __restrict__ wgt)
{
    __shared__ int cnt[NSLICE][NEXP];
    __shared__ int off[NSLICE][NEXP];
    __shared__ int ebase[NEXP + 1];
    __shared__ int is64_s;
    int tid = threadIdx.x;
    int wv = tid >> 6, lane = tid & 63;

    if (wv == 0) {
        int bad = (te_raw[2 * lane + 1] != 0u);
        unsigned long long m = __ballot(bad);
        if (lane == 0) is64_s = (m == 0ull);
    }
    __syncthreads();
    int is64 = is64_s;

    int c[NEXP] = {0,0,0,0,0,0,0,0};
    int eids[4];
    #pragma unroll
    for (int it = 0; it < 4; ++it) {
        int p = wv * 256 + it * 64 + lane;
        int eid = is64 ? (int)te_raw[2*p] : (int)te_raw[p];
        eids[it] = eid;
        #pragma unroll
        for (int e = 0; e < NEXP; ++e) {
            unsigned long long m = __ballot(eid == e);
            c[e] += __popcll(m);
        }
    }
    if (lane == 0)
        #pragma unroll
        for (int e = 0; e < NEXP; ++e) cnt[wv][e] = c[e];
    __syncthreads();

    if (tid < NEXP) {
        int run = 0;
        for (int s = 0; s < NSLICE; ++s) { off[s][tid] = run; run += cnt[s][tid]; }
        ebase[tid] = run;
    }
    __syncthreads();
    if (tid == 0) {
        int s = 0;
        for (int e = 0; e < NEXP; ++e) { int t = ebase[e]; ebase[e] = s; expert_off[e] = s; s += t; }
        ebase[NEXP] = s; expert_off[NEXP] = s;
        int nt = 0;
        for (int e = 0; e < NEXP; ++e)
            for (int m = ebase[e]; m < ebase[e + 1]; m += 128) { tte[nt] = e; ttm[nt] = m; ++nt; }
        *ntile_g = nt;
    }
    __syncthreads();

    int roff[NEXP];
    #pragma unroll
    for (int e = 0; e < NEXP; ++e) roff[e] = ebase[e] + off[wv][e];
    #pragma unroll
    for (int it = 0; it < 4; ++it) {
        int p = wv * 256 + it * 64 + lane;
        int eid = eids[it];
        int dest = -1;
        #pragma unroll
        for (int e = 0; e < NEXP; ++e) {
            unsigned long long m = __ballot(eid == e);
            if (eid == e) dest = roff[e] + __popcll(m & ((1ull << lane) - 1ull));
            roff[e] += __popcll(m);
        }
        tok[dest] = p >> 1;
        wgt[dest] = top_w[p];
    }
}

// ---------------- gather x rows -> bf16 -------------------------------------
__global__ void gather_kernel(const float* __restrict__ x,
                              const int* __restrict__ tok,
                              bf16* __restrict__ Xg)
{
    int p = blockIdx.x;
    int t = tok[p];
    const float4* src = (const float4*)(x + (size_t)t * HID);
    float4 v = src[threadIdx.x];
    bf16x4 o;
    o[0] = (bf16)v.x; o[1] = (bf16)v.y; o[2] = (bf16)v.z; o[3] = (bf16)v.w;
    *(bf16x4*)(Xg + (size_t)p * HID + threadIdx.x * 4) = o;
}

// --------- transpose v5: f32 [R][C] -> tile-image bf16, MLP+NT reads --------
__global__ void __launch_bounds__(256)
transpose_v5(const float* __restrict__ in1, bf16* __restrict__ out1,
             const float* __restrict__ in2, bf16* __restrict__ out2,
             int nz1, int R, int C)
{
    __shared__ u32 tile32[4][64 * 32];   // 32 KB
    int z = blockIdx.z;
    const float* in = (z < nz1) ? in1 : in2;
    bf16* o         = (z < nz1) ? out1 : out2;
    int e = (z < nz1) ? z : z - nz1;
    in += (size_t)e * R * C;
    o  += (size_t)e * R * C;
    int kt = blockIdx.x, nq = blockIdx.y;
    int k0 = kt * 64, c0 = nq * 256;
    int tid = threadIdx.x;
    int rbase = tid >> 6;
    int c4 = tid & 63;
    int grp = c4 >> 4, cq = c4 & 15;
    int fp0 = cq * 2;
    const float* base = in + (size_t)(k0 + rbase) * C + c0 + c4 * 4;
    f32x4v rb[16];
    #pragma unroll
    for (int it = 0; it < 16; ++it)
        rb[it] = __builtin_nontemporal_load((const f32x4v*)(base + (size_t)it * 4 * C));
    #pragma unroll
    for (int it = 0; it < 16; ++it) {
        int r = rbase + it * 4;
        union { bf16 h[2]; u32 w; } a, b;
        a.h[0] = (bf16)rb[it][0]; a.h[1] = (bf16)rb[it][1];
        b.h[0] = (bf16)rb[it][2]; b.h[1] = (bf16)rb[it][3];
        tile32[grp][r * 32 + (fp0       ^ (r & 31))] = a.w;
        tile32[grp][r * 32 + ((fp0 + 1) ^ (r & 31))] = b.w;
    }
    __syncthreads();
    int RT = R >> 6;
    #pragma unroll
    for (int it2 = 0; it2 < 8; ++it2) {
        int gg = it2 * 256 + tid;
        int group = gg >> 9, g = gg & 511;
        int f = g >> 3;
        int k8 = ((g & 7) ^ (f & 7)) * 8;
        union { bf16 h[8]; } pk;
        #pragma unroll
        for (int j = 0; j < 8; ++j) {
            u32 u = tile32[group][(k8 + j) * 32 + ((f >> 1) ^ ((k8 + j) & 31))];
            pk.h[j] = (f & 1) ? ((bf16*)&u)[1] : ((bf16*)&u)[0];
        }
        bf16* tbase = o + ((size_t)(nq * 4 + group) * RT + kt) * 4096;
        *(bf16x8*)(tbase + (size_t)g * 8) = *(bf16x8*)&pk;
    }
}

// ---------------- fused: ug-GEMM blocks + w_down transpose blocks -----------
__global__ void __launch_bounds__(256)
fused_ug(const bf16* __restrict__ Xg,
         const bf16* __restrict__ wuT, const bf16* __restrict__ wgT,
         const int* __restrict__ expert_off, const int* __restrict__ ntile_g,
         const int* __restrict__ tte, const int* __restrict__ ttm,
         bf16* __restrict__ H1,
         const float* __restrict__ Wd, bf16* __restrict__ wdT)
{
    __shared__ char ldsbuf[32768];
    int bid = blockIdx.x;
    int tid = threadIdx.x;

    if (bid >= NGEMM) {
        u32 (*tile32)[64 * 32] = (u32 (*)[64 * 32])ldsbuf;
        int tb = bid - NGEMM;            // 0..1023
        int e = tb >> 7;                 // 128 blocks/expert (32 kt x 4 nq)
        int rem = tb & 127;
        int nq = rem >> 5, kt = rem & 31;
        const float* in = Wd + (size_t)e * EXPELEM;
        bf16* o = wdT + (size_t)e * EXPELEM;
        int k0 = kt * 64, c0 = nq * 256;
        int rbase = tid >> 6;
        int c4 = tid & 63;
        int grp = c4 >> 4, cq = c4 & 15;
        int fp0 = cq * 2;
        const float* base = in + (size_t)(k0 + rbase) * HID + c0 + c4 * 4;
        f32x4v rb[16];
        #pragma unroll
        for (int it = 0; it < 16; ++it)
            rb[it] = __builtin_nontemporal_load((const f32x4v*)(base + (size_t)it * 4 * HID));
        #pragma unroll
        for (int it = 0; it < 16; ++it) {
            int r = rbase + it * 4;
            union { bf16 h[2]; u32 w; } a, b;
            a.h[0] = (bf16)rb[it][0]; a.h[1] = (bf16)rb[it][1];
            b.h[0] = (bf16)rb[it][2]; b.h[1] = (bf16)rb[it][3];
            tile32[grp][r * 32 + (fp0       ^ (r & 31))] = a.w;
            tile32[grp][r * 32 + ((fp0 + 1) ^ (r & 31))] = b.w;
        }
        __syncthreads();
        const int RT = FFN_ >> 6;        // 32
        #pragma unroll
        for (int it2 = 0; it2 < 8; ++it2) {
            int gg = it2 * 256 + tid;
            int group = gg >> 9, g = gg & 511;
            int f = g >> 3;
            int k8 = ((g & 7) ^ (f & 7)) * 8;
            union { bf16 h[8]; } pk;
            #pragma unroll
            for (int j = 0; j < 8; ++j) {
                u32 u = tile32[group][(k8 + j) * 32 + ((f >> 1) ^ ((k8 + j) & 31))];
                pk.h[j] = (f & 1) ? ((bf16*)&u)[1] : ((bf16*)&u)[0];
            }
            bf16* tbase = o + ((size_t)(nq * 4 + group) * RT + kt) * 4096;
            *(bf16x8*)(tbase + (size_t)g * 8) = *(bf16x8*)&pk;
        }
        return;
    }

    int ty = bid >> 5, bn = bid & 31;    // 32 N-tiles
    if (ty >= *ntile_g) return;
    int e = tte[ty];
    int m0 = ttm[ty];
    int p1 = expert_off[e + 1];
    int n0 = bn * 64;
    bf16* As  = (bf16*)ldsbuf;           // 16 KB
    bf16* Bus = (bf16*)(ldsbuf + 16384); // 8 KB
    bf16* Bgs = (bf16*)(ldsbuf + 24576); // 8 KB
    int lane = tid & 63, wv = tid >> 6;
    int wm = wv >> 1, wn = wv & 1;
    int l16 = lane & 15, lhi = lane >> 4;
    f32x4 accU[4][2] = {};
    f32x4 accG[4][2] = {};

    const bf16* aptr[4]; u32 alds[4];
    #pragma unroll
    for (int c = 0; c < 4; ++c) {
        int g = c * 256 + tid;
        int r = g >> 3, pos = g & 7;
        int gr = m0 + r; if (gr >= p1) gr = p1 - 1;
        int gsrc = pos ^ (r & 7);
        aptr[c] = Xg + (size_t)gr * HID + gsrc * 8;
        alds[c] = g * 16;
    }
    size_t tb0 = (size_t)e * EXPELEM + (size_t)(n0 >> 6) * (HID >> 6) * 4096;
    const bf16* buptr[2]; const bf16* bgptr[2]; u32 blds[2];
    #pragma unroll
    for (int c = 0; c < 2; ++c) {
        int g = c * 256 + tid;
        buptr[c] = wuT + tb0 + (size_t)g * 8;
        bgptr[c] = wgT + tb0 + (size_t)g * 8;
        blds[c] = g * 16;
    }
    u32 aro[2][4], bro[2][2];
    #pragma unroll
    for (int ks = 0; ks < 2; ++ks) {
        #pragma unroll
        for (int fm = 0; fm < 4; ++fm) {
            int r = wm * 64 + fm * 16 + l16;
            aro[ks][fm] = r * 128 + ((u32)((ks * 4 + lhi) ^ (r & 7))) * 16;
        }
        #pragma unroll
        for (int fn = 0; fn < 2; ++fn) {
            int fr = wn * 32 + fn * 16 + l16;
            bro[ks][fn] = fr * 128 + ((u32)((ks * 4 + lhi) ^ (fr & 7))) * 16;
        }
    }

    for (int t = 0; t < HID / 64; ++t) {
        #pragma unroll
        for (int c = 0; c < 4; ++c) { gld16(aptr[c], (char*)As + alds[c]); aptr[c] += 64; }
        #pragma unroll
        for (int c = 0; c < 2; ++c) {
            gld16(buptr[c], (char*)Bus + blds[c]); buptr[c] += 4096;
            gld16(bgptr[c], (char*)Bgs + blds[c]); bgptr[c] += 4096;
        }
        __syncthreads();
        #pragma unroll
        for (int ks = 0; ks < 2; ++ks) {
            bf16x8 af[4];
            #pragma unroll
            for (int fm = 0; fm < 4; ++fm)
                af[fm] = *(const bf16x8*)((char*)As + aro[ks][fm]);
            #pragma unroll
            for (int fn = 0; fn < 2; ++fn) {
                bf16x8 bu = *(const bf16x8*)((char*)Bus + bro[ks][fn]);
                bf16x8 bg = *(const bf16x8*)((char*)Bgs + bro[ks][fn]);
                #pragma unroll
                for (int fm = 0; fm < 4; ++fm) {
                    accU[fm][fn] = __builtin_amdgcn_mfma_f32_16x16x32_bf16(af[fm], bu, accU[fm][fn], 0, 0, 0);
                    accG[fm][fn] = __builtin_amdgcn_mfma_f32_16x16x32_bf16(af[fm], bg, accG[fm][fn], 0, 0, 0);
                }
            }
        }
        __syncthreads();
    }
    #pragma unroll
    for (int fm = 0; fm < 4; ++fm)
    #pragma unroll
    for (int fn = 0; fn < 2; ++fn)
    #pragma unroll
    for (int rg = 0; rg < 4; ++rg) {
        int r = m0 + wm * 64 + fm * 16 + lhi * 4 + rg;
        if (r < p1) {
            float u = accU[fm][fn][rg], g = accG[fm][fn][rg];
            float h = (u / (1.f + __expf(-u))) * g;
            int fc = n0 + wn * 32 + fn * 16 + l16;
            H1[(size_t)r * FFN_ + fc] = (bf16)h;
        }
    }
}

// ---------------- GEMM2 (image weights): ------------------------------------
__global__ void __launch_bounds__(256)
moe_down(const bf16* __restrict__ H1, const bf16* __restrict__ wdT,
         const int* __restrict__ expert_off, const int* __restrict__ ntile_g,
         const int* __restrict__ tte, const int* __restrict__ ttm,
         const int* __restrict__ tok, const float* __restrict__ wgt,
         float* __restrict__ out)
{
    int ty = blockIdx.y;
    if (ty >= *ntile_g) return;
    int e = tte[ty];
    int m0 = ttm[ty];
    int p1 = expert_off[e + 1];
    int n0 = blockIdx.x * 64;
    __shared__ bf16 As[128 * 64];
    __shared__ bf16 Bs [64 * 64];
    __shared__ float wgt_s[128];
    __shared__ int   tok_s[128];
    int tid = threadIdx.x, lane = tid & 63, wv = tid >> 6;
    int wm = wv >> 1, wn = wv & 1;
    int l16 = lane & 15, lhi = lane >> 4;
    if (tid < 128) {
        int r = m0 + tid;
        if (r < p1) { wgt_s[tid] = wgt[r]; tok_s[tid] = tok[r]; }
        else        { wgt_s[tid] = 0.f;    tok_s[tid] = 0; }
    }
    f32x4 acc[4][2] = {};

    const bf16* aptr[4]; u32 alds[4];
    #pragma unroll
    for (int c = 0; c < 4; ++c) {
        int g = c * 256 + tid;
        int r = g >> 3, pos = g & 7;
        int gr = m0 + r; if (gr >= p1) gr = p1 - 1;
        int gsrc = pos ^ (r & 7);
        aptr[c] = H1 + (size_t)gr * FFN_ + gsrc * 8;
        alds[c] = g * 16;
    }
    size_t tb0 = (size_t)e * EXPELEM + (size_t)(n0 >> 6) * (FFN_ >> 6) * 4096;
    const bf16* bptr[2]; u32 blds[2];
    #pragma unroll
    for (int c = 0; c < 2; ++c) {
        int g = c * 256 + tid;
        bptr[c] = wdT + tb0 + (size_t)g * 8;
        blds[c] = g * 16;
    }
    u32 aro[2][4], bro[2][2];
    #pragma unroll
    for (int ks = 0; ks < 2; ++ks) {
        #pragma unroll
        for (int fm = 0; fm < 4; ++fm) {
            int r = wm * 64 + fm * 16 + l16;
            aro[ks][fm] = r * 128 + ((u32)((ks * 4 + lhi) ^ (r & 7))) * 16;
        }
        #pragma unroll
        for (int fn = 0; fn < 2; ++fn) {
            int fr = wn * 32 + fn * 16 + l16;
            bro[ks][fn] = fr * 128 + ((u32)((ks * 4 + lhi) ^ (fr & 7))) * 16;
        }
    }

    for (int t = 0; t < FFN_ / 64; ++t) {
        #pragma unroll
        for (int c = 0; c < 4; ++c) { gld16(aptr[c], (char*)As + alds[c]); aptr[c] += 64; }
        #pragma unroll
        for (int c = 0; c < 2; ++c) { gld16(bptr[c], (char*)Bs + blds[c]); bptr[c] += 4096; }
        __syncthreads();
        #pragma unroll
        for (int ks = 0; ks < 2; ++ks) {
            bf16x8 af[4];
            #pragma unroll
            for (int fm = 0; fm < 4; ++fm)
                af[fm] = *(const bf16x8*)((char*)As + aro[ks][fm]);
            #pragma unroll
            for (int fn = 0; fn < 2; ++fn) {
                bf16x8 bd = *(const bf16x8*)((char*)Bs + bro[ks][fn]);
                #pragma unroll
                for (int fm = 0; fm < 4; ++fm)
                    acc[fm][fn] = __builtin_amdgcn_mfma_f32_16x16x32_bf16(af[fm], bd, acc[fm][fn], 0, 0, 0);
            }
        }
        __syncthreads();
    }
    #pragma unroll
    for (int fm = 0; fm < 4; ++fm)
    #pragma unroll
    for (int fn = 0; fn < 2; ++fn)
    #pragma unroll
    for (int rg = 0; rg < 4; ++rg) {
        int rl = wm * 64 + fm * 16 + lhi * 4 + rg;
        if (m0 + rl < p1) {
            float v = acc[fm][fn][rg] * wgt_s[rl];
            atomicAdd(out + (size_t)tok_s[rl] * HID + n0 + wn * 32 + fn * 16 + l16, v);
        }
    }
}

extern "C" void kernel_launch(void* const* d_in, const int* in_sizes, int n_in,
                              void* d_out, int out_size, void* d_ws, size_t ws_size,
                              hipStream_t stream)
{
    const float*    x      = (const float*)d_in[0];
    const float*    top_w  = (const float*)d_in[2];
    const uint32_t* te     = (const uint32_t*)d_in[3];
    const float*    w_up   = (const float*)d_in[4];
    const float*    w_gate = (const float*)d_in[5];
    const float*    w_down = (const float*)d_in[6];
    float* out = (float*)d_out;
    char*  ws  = (char*)d_ws;

    int*   expert_off = (int*)(ws + OFF_EXP);
    int*   ntile_g    = (int*)(ws + OFF_NT);
    int*   tte        = (int*)(ws + OFF_TTE);
    int*   ttm        = (int*)(ws + OFF_TTM);
    int*   tok        = (int*)(ws + OFF_TOK);
    float* wgt        = (float*)(ws + OFF_WGT);
    bf16*  Xg         = (bf16*)(ws + OFF_XG);
    bf16*  H1         = (bf16*)(ws + OFF_H1);
    bf16*  WT         = (bf16*)(ws + OFF_WT);
    bf16*  wuT = WT;
    bf16*  wgT = WT + 8 * EXPELEM;     // +32 MB
    bf16*  wdT = WT + 16 * EXPELEM;    // +64 MB

    hipMemsetAsync(out, 0, (size_t)out_size * sizeof(float), stream);
    hipLaunchKernelGGL(route_kernel, dim3(1), dim3(1024), 0, stream,
                       te, top_w, expert_off, ntile_g, tte, ttm, tok, wgt);
    hipLaunchKernelGGL(gather_kernel, dim3(NPAIR), dim3(256), 0, stream,
                       x, tok, Xg);

    // up/gate weight conversion (v5)
    hipLaunchKernelGGL(transpose_v5, dim3(HID / 64, FFN_ / 256, 16), dim3(256), 0, stream,
                       w_up, wuT, w_gate, wgT, 8, HID, FFN_);

    // fused: ug GEMM (1280 blocks) + w_down transpose (1024 blocks)
    hipLaunchKernelGGL(fused_ug, dim3(NGEMM + 1024), dim3(256), 0, stream,
                       Xg, wuT, wgT, expert_off, ntile_g, tte, ttm, H1,
                       w_down, wdT);

    hipLaunchKernelGGL(moe_down, dim3(HID / 64, MAXTILE), dim3(256), 0, stream,
                       H1, wdT, expert_off, ntile_g, tte, ttm, tok, wgt, out);
}